// Round 8
// baseline (568.871 us; speedup 1.0000x reference)
//
#include <hip/hip_runtime.h>
#include <cstddef>
#include <cstdint>

// Problem constants (match reference setup_inputs()).
#define N_NODES 100000
#define N_EDGES 640000
#define EMBD    128
#define NBATCH  16384
#define CHUNK   1024
#define NCHUNK  ((N_NODES + CHUNK - 1) / CHUNK)   // 98

// MFMA fragment types (guide §3: bf16 16x16x32 -> short8 / float4).
typedef short bf16x8 __attribute__((ext_vector_type(8)));
typedef float f32x4  __attribute__((ext_vector_type(4)));

// ---------------------------------------------------------------------------
// Split-bf16: uint32 = bf16(x) [hi16] | bf16(x - hi) [lo16], RNE both.
// a*b via ah*bh + ah*bl + al*bh (3 MFMAs) drops only lo*lo (~2^-18 rel).
// ---------------------------------------------------------------------------
__device__ __forceinline__ unsigned pack_split(float x) {
    unsigned u  = __float_as_uint(x);
    unsigned hi = (u + 0x7fffu + ((u >> 16) & 1u)) & 0xffff0000u;
    float    lo = x - __uint_as_float(hi);
    unsigned ul = __float_as_uint(lo);
    unsigned lw = ((ul + 0x7fffu + ((ul >> 16) & 1u)) >> 16) & 0xffffu;
    return hi | lw;
}
__device__ __forceinline__ float unpack_split(unsigned u) {
    return __uint_as_float(u & 0xffff0000u) + __uint_as_float(u << 16);
}

// ---------------------------------------------------------------------------
// Fused: pack embedding to split-bf16 + per-dst-node edge histogram.
// ---------------------------------------------------------------------------
__global__ __launch_bounds__(256) void pack_hist(
    const float* __restrict__ emb, unsigned* __restrict__ xslot,
    const int* __restrict__ ei, int* __restrict__ cursor, int n, int E)
{
    const int i = blockIdx.x * 256 + threadIdx.x;
    if (i < n) xslot[i] = pack_split(emb[i]);
    if (i < E) atomicAdd(&cursor[ei[E + i]], 1);
}

// ---------------------------------------------------------------------------
// Pre-split both layers' weights into TRANSPOSED bf16 hi/lo planes:
// Wt*[col][k], k=0..383 (rows 0-255 = w_rel flat, 256-383 = w_root).
// ---------------------------------------------------------------------------
__global__ void wpack_kernel(
    const float* __restrict__ w1_rel, const float* __restrict__ w1_root,
    const float* __restrict__ w2_rel, const float* __restrict__ w2_root,
    unsigned short* __restrict__ WtH1, unsigned short* __restrict__ WtL1,
    unsigned short* __restrict__ WtH2, unsigned short* __restrict__ WtL2)
{
    const int col = blockIdx.x;
    const int k   = threadIdx.x;
    const size_t o = (size_t)col * 384 + k;
    {
        const float x = (k < 256) ? w1_rel[(size_t)k * EMBD + col]
                                  : w1_root[(size_t)(k - 256) * EMBD + col];
        const unsigned p = pack_split(x);
        WtH1[o] = (unsigned short)(p >> 16);
        WtL1[o] = (unsigned short)(p & 0xffffu);
    }
    {
        const float x = (k < 256) ? w2_rel[(size_t)k * EMBD + col]
                                  : w2_root[(size_t)(k - 256) * EMBD + col];
        const unsigned p = pack_split(x);
        WtH2[o] = (unsigned short)(p >> 16);
        WtL2[o] = (unsigned short)(p & 0xffffu);
    }
}

// ---------------------------------------------------------------------------
// Hierarchical exclusive scan (counts -> starts), in place.
// ---------------------------------------------------------------------------
__global__ __launch_bounds__(256) void scan_local(
    int* __restrict__ cursor, int* __restrict__ bsum, int n)
{
    __shared__ int part[256];
    const int t    = threadIdx.x;
    const int base = blockIdx.x * CHUNK + t * 4;
    int v[4];
    int s = 0;
#pragma unroll
    for (int i = 0; i < 4; ++i) {
        const int idx = base + i;
        v[i] = (idx < n) ? cursor[idx] : 0;
        s += v[i];
    }
    part[t] = s;
    __syncthreads();
    for (int off = 1; off < 256; off <<= 1) {
        const int add = (t >= off) ? part[t - off] : 0;
        __syncthreads();
        part[t] += add;
        __syncthreads();
    }
    if (t == 255) bsum[blockIdx.x] = part[255];
    int run = (t == 0) ? 0 : part[t - 1];
#pragma unroll
    for (int i = 0; i < 4; ++i) {
        const int idx = base + i;
        if (idx < n) { cursor[idx] = run; run += v[i]; }
    }
}

__global__ __launch_bounds__(128) void scan_bsum(int* __restrict__ bsum)
{
    __shared__ int part[128];
    const int t = threadIdx.x;
    const int v = (t < NCHUNK) ? bsum[t] : 0;
    part[t] = v;
    __syncthreads();
    for (int off = 1; off < 128; off <<= 1) {
        const int add = (t >= off) ? part[t - off] : 0;
        __syncthreads();
        part[t] += add;
        __syncthreads();
    }
    if (t < NCHUNK) bsum[t] = part[t] - v;    // exclusive
}

__global__ __launch_bounds__(256) void scan_add(
    int* __restrict__ cursor, const int* __restrict__ bsum, int n)
{
    const int off  = bsum[blockIdx.x];
    const int base = blockIdx.x * CHUNK + threadIdx.x * 4;
#pragma unroll
    for (int i = 0; i < 4; ++i) {
        const int idx = base + i;
        if (idx < n) cursor[idx] += off;
    }
}

// ---------------------------------------------------------------------------
// Bucket edges into dst-sorted order. After this, cursor[n] == END of node
// n's run. Record: src (17b) | rel (1b @17) in .x, weight bits in .y.
// ---------------------------------------------------------------------------
__global__ __launch_bounds__(256) void bucket_kernel(
    const int* __restrict__ ei, const int* __restrict__ et,
    const float* __restrict__ ew, int* __restrict__ cursor,
    int2* __restrict__ srec, int E)
{
    const int e = blockIdx.x * 256 + threadIdx.x;
    if (e >= E) return;
    const int src = ei[e];
    const int dst = ei[E + e];
    const int r   = et[e];
    const int pos = atomicAdd(&cursor[dst], 1);
    srec[pos] = make_int2(src | (r << 17), __float_as_int(ew[e]));
}

// ---------------------------------------------------------------------------
// One wave per dst node: gathers PACKED split-bf16 rows (uint2/lane),
// fp32 register accumulation of both relations, packed stores. No atomics.
// ---------------------------------------------------------------------------
__global__ __launch_bounds__(256) void accum_csr(
    const unsigned* __restrict__ xp, const int2* __restrict__ srec,
    const int* __restrict__ cursor, unsigned* __restrict__ Ap, int N)
{
    const int wid  = blockIdx.x * 4 + (threadIdx.x >> 6);   // dst node
    const int lane = threadIdx.x & 63;
    const int s = (wid == 0) ? 0 : cursor[wid - 1];
    const int e = cursor[wid];

    float ax = 0.f, ay = 0.f, bx = 0.f, by = 0.f;
    int i = s;
    for (; i + 3 < e; i += 4) {
        const int2 r0 = srec[i];
        const int2 r1 = srec[i + 1];
        const int2 r2 = srec[i + 2];
        const int2 r3 = srec[i + 3];
        const uint2 g0 = ((const uint2*)(xp + (size_t)(r0.x & 0x1FFFF) * EMBD))[lane];
        const uint2 g1 = ((const uint2*)(xp + (size_t)(r1.x & 0x1FFFF) * EMBD))[lane];
        const uint2 g2 = ((const uint2*)(xp + (size_t)(r2.x & 0x1FFFF) * EMBD))[lane];
        const uint2 g3 = ((const uint2*)(xp + (size_t)(r3.x & 0x1FFFF) * EMBD))[lane];
        const float w0 = __int_as_float(r0.y);
        const float w1 = __int_as_float(r1.y);
        const float w2 = __int_as_float(r2.y);
        const float w3 = __int_as_float(r3.y);
        {
            const float vx = unpack_split(g0.x), vy = unpack_split(g0.y);
            if (r0.x & (1 << 17)) { bx += vx * w0; by += vy * w0; }
            else                  { ax += vx * w0; ay += vy * w0; }
        }
        {
            const float vx = unpack_split(g1.x), vy = unpack_split(g1.y);
            if (r1.x & (1 << 17)) { bx += vx * w1; by += vy * w1; }
            else                  { ax += vx * w1; ay += vy * w1; }
        }
        {
            const float vx = unpack_split(g2.x), vy = unpack_split(g2.y);
            if (r2.x & (1 << 17)) { bx += vx * w2; by += vy * w2; }
            else                  { ax += vx * w2; ay += vy * w2; }
        }
        {
            const float vx = unpack_split(g3.x), vy = unpack_split(g3.y);
            if (r3.x & (1 << 17)) { bx += vx * w3; by += vy * w3; }
            else                  { ax += vx * w3; ay += vy * w3; }
        }
    }
    for (; i < e; ++i) {
        const int2 r0 = srec[i];
        const uint2 g0 = ((const uint2*)(xp + (size_t)(r0.x & 0x1FFFF) * EMBD))[lane];
        const float w0 = __int_as_float(r0.y);
        const float vx = unpack_split(g0.x), vy = unpack_split(g0.y);
        if (r0.x & (1 << 17)) { bx += vx * w0; by += vy * w0; }
        else                  { ax += vx * w0; ay += vy * w0; }
    }
    ((uint2*)(Ap + (size_t)wid * EMBD))[lane]       = make_uint2(pack_split(ax), pack_split(ay));
    ((uint2*)(Ap + ((size_t)N + wid) * EMBD))[lane] = make_uint2(pack_split(bx), pack_split(by));
}

// ---------------------------------------------------------------------------
// Split-bf16 MFMA GEMM (round-6 structure + Wt-plane B staging):
// out[M,128] = (S0|S1|S2)[M,384] @ W[384,128] + bias.
// Per chunk: barrier -> stage A (uint4 loads, de-interleave, b128 writes)
// + stage B (pure uint4 copies from pre-split planes) -> barrier -> 48 MFMAs.
// No registers live across the MFMA block (round-7's prefetch spilled:
// WRITE_SIZE 50->67 MB, VGPR 128->84, dur 73->101 us — reverted).
// HAVE_WT template keeps the fallback's pack_split code out of the hot
// variant's register allocation.
// Fragment layouts (m89/m120 verified): A[m=lane&15][k=quad*8+j];
// C/D col=lane&15, row=quad*4+reg. LDS rows 80 B so b128 reads are cheap.
// Each block reads only rows [m0,m0+128) of S* and writes the same rows of
// out strictly after all its reads -> out may alias any S*.
// ---------------------------------------------------------------------------
template <bool HAVE_WT>
__global__ __launch_bounds__(256) void gemm_mfma(
    const unsigned* __restrict__ S0, const unsigned* __restrict__ S1,
    const unsigned* __restrict__ S2,
    const unsigned short* __restrict__ WtH, const unsigned short* __restrict__ WtL,
    const float* __restrict__ wrel, const float* __restrict__ wroot,
    const float* __restrict__ bias, const float* __restrict__ lng,
    const float* __restrict__ lnb, void* __restrict__ outv,
    int M, int do_ln)
{
    __shared__ unsigned short AsH[128 * 40], AsL[128 * 40];   // 10 KB each
    __shared__ unsigned short BsH[128 * 40], BsL[128 * 40];
    __shared__ float lnbuf[2][128][2];

    const int t    = threadIdx.x;
    const int wave = t >> 6;
    const int lane = t & 63;
    const int q    = lane >> 4;
    const int n    = lane & 15;
    const int wrow = wave & 1;
    const int wcol = wave >> 1;
    const int m0   = blockIdx.x * 128;

    const int arow   = t >> 1;       // 0..127
    const int ahalf  = t & 1;        // which 16-elem half of the 32-k chunk
    const int bcol   = t & 127;
    const int bplane = t >> 7;       // 0 = hi, 1 = lo

    f32x4 acc[4][4];
#pragma unroll
    for (int rt = 0; rt < 4; ++rt)
#pragma unroll
        for (int ct = 0; ct < 4; ++ct)
            acc[rt][ct] = (f32x4){0.f, 0.f, 0.f, 0.f};

    for (int kc = 0; kc < 12; ++kc) {
        __syncthreads();   // previous chunk's frag reads done before overwrite

        // ---- A stage: 128x32 packed -> split planes, b128 writes ----
        {
            const unsigned* Sp = (kc < 4) ? S0 : (kc < 8) ? S1 : S2;
            const int rg = m0 + arow;
            uint4 u0, u1, u2, u3;
            if (rg < M) {
                const unsigned* p = Sp + (size_t)rg * EMBD + (kc & 3) * 32 + ahalf * 16;
                u0 = *(const uint4*)(p);
                u1 = *(const uint4*)(p + 4);
                u2 = *(const uint4*)(p + 8);
                u3 = *(const uint4*)(p + 12);
            } else {
                u0 = u1 = u2 = u3 = make_uint4(0u, 0u, 0u, 0u);
            }
            unsigned uu[16] = {u0.x, u0.y, u0.z, u0.w, u1.x, u1.y, u1.z, u1.w,
                               u2.x, u2.y, u2.z, u2.w, u3.x, u3.y, u3.z, u3.w};
            unsigned dh[8], dl[8];
#pragma unroll
            for (int i = 0; i < 8; ++i) {
                const unsigned e0 = uu[2 * i], e1 = uu[2 * i + 1];
                dh[i] = (e1 & 0xffff0000u) | (e0 >> 16);
                dl[i] = (e1 << 16) | (e0 & 0xffffu);
            }
            uint4* pH = (uint4*)(AsH + arow * 40 + ahalf * 16);
            uint4* pL = (uint4*)(AsL + arow * 40 + ahalf * 16);
            pH[0] = make_uint4(dh[0], dh[1], dh[2], dh[3]);
            pH[1] = make_uint4(dh[4], dh[5], dh[6], dh[7]);
            pL[0] = make_uint4(dl[0], dl[1], dl[2], dl[3]);
            pL[1] = make_uint4(dl[4], dl[5], dl[6], dl[7]);
        }
        // ---- B stage ----
        if (HAVE_WT) {
            // Pure copy: 64 B of one plane of one column's 32-k chunk.
            const unsigned short* W = bplane ? WtL : WtH;
            const uint4* p = (const uint4*)(W + (size_t)bcol * 384 + kc * 32);
            uint4* pB = (uint4*)((bplane ? BsL : BsH) + bcol * 40);
            pB[0] = p[0]; pB[1] = p[1]; pB[2] = p[2]; pB[3] = p[3];
        } else {
            // Fallback: split fp32 W on the fly (16 values, both planes).
            const int bkh = t >> 7;
            unsigned pk[16];
#pragma unroll
            for (int j = 0; j < 16; ++j) {
                const int kv = kc * 32 + bkh * 16 + j;
                const float x = (kv < 256) ? wrel[(size_t)kv * EMBD + bcol]
                                           : wroot[(size_t)(kv - 256) * EMBD + bcol];
                pk[j] = pack_split(x);
            }
            unsigned dh[8], dl[8];
#pragma unroll
            for (int i = 0; i < 8; ++i) {
                const unsigned e0 = pk[2 * i], e1 = pk[2 * i + 1];
                dh[i] = (e1 & 0xffff0000u) | (e0 >> 16);
                dl[i] = (e1 << 16) | (e0 & 0xffffu);
            }
            uint4* pH = (uint4*)(BsH + bcol * 40 + bkh * 16);
            uint4* pL = (uint4*)(BsL + bcol * 40 + bkh * 16);
            pH[0] = make_uint4(dh[0], dh[1], dh[2], dh[3]);
            pH[1] = make_uint4(dh[4], dh[5], dh[6], dh[7]);
            pL[0] = make_uint4(dl[0], dl[1], dl[2], dl[3]);
            pL[1] = make_uint4(dl[4], dl[5], dl[6], dl[7]);
        }
        __syncthreads();

        // ---- fragments + MFMA ----
        bf16x8 ah[4], al[4];
#pragma unroll
        for (int rt = 0; rt < 4; ++rt) {
            const int r = wrow * 64 + rt * 16 + n;
            ah[rt] = *(const bf16x8*)&AsH[r * 40 + q * 8];
            al[rt] = *(const bf16x8*)&AsL[r * 40 + q * 8];
        }
#pragma unroll
        for (int ct = 0; ct < 4; ++ct) {
            const int c = wcol * 64 + ct * 16 + n;
            const bf16x8 bh = *(const bf16x8*)&BsH[c * 40 + q * 8];
            const bf16x8 bl = *(const bf16x8*)&BsL[c * 40 + q * 8];
#pragma unroll
            for (int rt = 0; rt < 4; ++rt) {
                acc[rt][ct] = __builtin_amdgcn_mfma_f32_16x16x32_bf16(ah[rt], bh, acc[rt][ct], 0, 0, 0);
                acc[rt][ct] = __builtin_amdgcn_mfma_f32_16x16x32_bf16(ah[rt], bl, acc[rt][ct], 0, 0, 0);
                acc[rt][ct] = __builtin_amdgcn_mfma_f32_16x16x32_bf16(al[rt], bh, acc[rt][ct], 0, 0, 0);
            }
        }
    }

    // ---- epilogue ----
    float bb[4], gg[4], tb[4];
#pragma unroll
    for (int ct = 0; ct < 4; ++ct) {
        const int c = wcol * 64 + ct * 16 + n;
        bb[ct] = bias[c];
        gg[ct] = do_ln ? lng[c] : 0.f;
        tb[ct] = do_ln ? lnb[c] : 0.f;
    }

    if (do_ln) {
#pragma unroll
        for (int rt = 0; rt < 4; ++rt)
#pragma unroll
            for (int r = 0; r < 4; ++r) {
                float s = 0.f, sq = 0.f;
#pragma unroll
                for (int ct = 0; ct < 4; ++ct) {
                    float v = acc[rt][ct][r] + bb[ct];
                    v = fmaxf(v, 0.f);
                    acc[rt][ct][r] = v;
                    s += v; sq += v * v;
                }
#pragma unroll
                for (int off = 1; off < 16; off <<= 1) {
                    s  += __shfl_xor(s,  off, 64);
                    sq += __shfl_xor(sq, off, 64);
                }
                if (n == 0) {
                    const int row = wrow * 64 + rt * 16 + q * 4 + r;
                    lnbuf[wcol][row][0] = s;
                    lnbuf[wcol][row][1] = sq;
                }
            }
        __syncthreads();
        unsigned* outp = (unsigned*)outv;
#pragma unroll
        for (int rt = 0; rt < 4; ++rt)
#pragma unroll
            for (int r = 0; r < 4; ++r) {
                const int row = wrow * 64 + rt * 16 + q * 4 + r;
                const int rg  = m0 + row;
                const float s    = lnbuf[0][row][0] + lnbuf[1][row][0];
                const float sq   = lnbuf[0][row][1] + lnbuf[1][row][1];
                const float mu   = s * (1.0f / 128.0f);
                const float var  = sq * (1.0f / 128.0f) - mu * mu;
                const float rstd = rsqrtf(var + 1e-5f);
                if (rg < M) {
#pragma unroll
                    for (int ct = 0; ct < 4; ++ct) {
                        const int c = wcol * 64 + ct * 16 + n;
                        const float v = (acc[rt][ct][r] - mu) * rstd * gg[ct] + tb[ct];
                        outp[(size_t)rg * EMBD + c] = pack_split(v);
                    }
                }
            }
    } else {
        float* outp = (float*)outv;
#pragma unroll
        for (int rt = 0; rt < 4; ++rt)
#pragma unroll
            for (int r = 0; r < 4; ++r) {
                const int rg = m0 + wrow * 64 + rt * 16 + q * 4 + r;
                if (rg < M) {
#pragma unroll
                    for (int ct = 0; ct < 4; ++ct) {
                        const int c = wcol * 64 + ct * 16 + n;
                        outp[(size_t)rg * EMBD + c] = acc[rt][ct][r] + bb[ct];
                    }
                }
            }
    }
}

// ---------------------------------------------------------------------------
// Fused head: gather u/v, l2 norms, GMF, MLP 256->128->64->32, out proj,
// sigmoid. 16 batch rows per 256-thread block, everything staged in LDS.
// ---------------------------------------------------------------------------
__global__ __launch_bounds__(256) void head_kernel(
    const float* __restrict__ x2, const int* __restrict__ ui, const int* __restrict__ vi,
    const float* __restrict__ mw0, const float* __restrict__ mb0,
    const float* __restrict__ mw1, const float* __restrict__ mb1,
    const float* __restrict__ mw2, const float* __restrict__ mb2,
    const float* __restrict__ ow, const float* __restrict__ ob,
    float* __restrict__ out, int B)
{
    __shared__ float h0[16][256];
    __shared__ float h1[16][128];
    __shared__ float h2[16][64];
    __shared__ float h3[16][32];
    __shared__ float ps_u[16][16], ps_v[16][16];
    __shared__ float inv_nunv[16];
    __shared__ float pg[16][16], ph[16][16];

    const int t   = threadIdx.x;
    const int bb0 = blockIdx.x * 16;

    for (int r = 0; r < 16; ++r) {
        const int b   = bb0 + r;
        const int idx = (t < 128) ? ui[b] : vi[b];
        const int c   = t & 127;
        h0[r][t] = x2[(size_t)idx * EMBD + c];
    }
    __syncthreads();

    {
        const int row = t >> 4, sub = t & 15;
        float su = 0.f, sv = 0.f;
#pragma unroll
        for (int k = 0; k < 8; ++k) {
            const float a = h0[row][sub + 16 * k];       su += a * a;
            const float b = h0[row][128 + sub + 16 * k]; sv += b * b;
        }
        ps_u[row][sub] = su; ps_v[row][sub] = sv;
    }
    __syncthreads();
    if (t < 16) {
        float su = 0.f, sv = 0.f;
#pragma unroll
        for (int k = 0; k < 16; ++k) { su += ps_u[t][k]; sv += ps_v[t][k]; }
        const float nu = fmaxf(sqrtf(su), 1e-12f);
        const float nv = fmaxf(sqrtf(sv), 1e-12f);
        inv_nunv[t] = 1.0f / (nu * nv);
    }
    __syncthreads();

    {
        const int c = t & 127, rr = t >> 7;
        float acc[8];
#pragma unroll
        for (int j = 0; j < 8; ++j) acc[j] = 0.f;
        for (int i = 0; i < 256; i += 4) {
            const float w0 = mw0[(i + 0) * 128 + c];
            const float w1 = mw0[(i + 1) * 128 + c];
            const float w2 = mw0[(i + 2) * 128 + c];
            const float w3 = mw0[(i + 3) * 128 + c];
#pragma unroll
            for (int j = 0; j < 8; ++j) {
                const float4 a = *(const float4*)&h0[rr * 8 + j][i];
                acc[j] += a.x * w0 + a.y * w1 + a.z * w2 + a.w * w3;
            }
        }
        const float bv = mb0[c];
#pragma unroll
        for (int j = 0; j < 8; ++j) h1[rr * 8 + j][c] = fmaxf(acc[j] + bv, 0.f);
    }
    __syncthreads();

    {
        const int c = t & 63, g = t >> 6;
        float acc[4] = {0.f, 0.f, 0.f, 0.f};
        for (int i = 0; i < 128; i += 4) {
            const float w0 = mw1[(i + 0) * 64 + c];
            const float w1 = mw1[(i + 1) * 64 + c];
            const float w2 = mw1[(i + 2) * 64 + c];
            const float w3 = mw1[(i + 3) * 64 + c];
#pragma unroll
            for (int j = 0; j < 4; ++j) {
                const float4 a = *(const float4*)&h1[g * 4 + j][i];
                acc[j] += a.x * w0 + a.y * w1 + a.z * w2 + a.w * w3;
            }
        }
        const float bv = mb1[c];
#pragma unroll
        for (int j = 0; j < 4; ++j) h2[g * 4 + j][c] = fmaxf(acc[j] + bv, 0.f);
    }
    __syncthreads();

    {
        const int c = t & 31, g = t >> 5;
        float acc[2] = {0.f, 0.f};
        for (int i = 0; i < 64; i += 4) {
            const float w0 = mw2[(i + 0) * 32 + c];
            const float w1 = mw2[(i + 1) * 32 + c];
            const float w2 = mw2[(i + 2) * 32 + c];
            const float w3 = mw2[(i + 3) * 32 + c];
#pragma unroll
            for (int j = 0; j < 2; ++j) {
                const float4 a = *(const float4*)&h2[g * 2 + j][i];
                acc[j] += a.x * w0 + a.y * w1 + a.z * w2 + a.w * w3;
            }
        }
        const float bv = mb2[c];
#pragma unroll
        for (int j = 0; j < 2; ++j) h3[g * 2 + j][c] = fmaxf(acc[j] + bv, 0.f);
    }
    __syncthreads();

    {
        const int row = t >> 4, sub = t & 15;
        float pgv = 0.f;
#pragma unroll
        for (int k = 0; k < 8; ++k) {
            const int c = sub + 16 * k;
            pgv += h0[row][c] * h0[row][128 + c] * ow[c];
        }
        const float phv = h3[row][sub]      * ow[128 + sub]
                        + h3[row][sub + 16] * ow[144 + sub];
        pg[row][sub] = pgv; ph[row][sub] = phv;
    }
    __syncthreads();
    if (t < 16) {
        float sg = 0.f, sh = 0.f;
#pragma unroll
        for (int k = 0; k < 16; ++k) { sg += pg[t][k]; sh += ph[t][k]; }
        const float z = sg * inv_nunv[t] + sh + ob[0];
        out[bb0 + t] = 1.0f / (1.0f + expf(-z));
    }
}

// ---------------------------------------------------------------------------
// Launch. ws layout (~159.5 MB; Wt planes guarded by ws_size check):
//   Ap[2][N][128]  u32 102.4 MB  (packed aggregates; gemm-2 writes fp32 x2
//                                 into Ap[0] rows, row-aliased safe)
//   xslot[N][128]  u32  51.2 MB  (packed emb -> packed x1, row-aliased)
//   srec[E] int2         5.12 MB
//   cursor[N]            0.4 MB
//   bsum[NCHUNK]         ~400 B
//   WtH1/WtL1/WtH2/WtL2  4 x 96 KB (pre-split transposed weight planes)
// ---------------------------------------------------------------------------
extern "C" void kernel_launch(void* const* d_in, const int* in_sizes, int n_in,
                              void* d_out, int out_size, void* d_ws, size_t ws_size,
                              hipStream_t stream)
{
    const int*   ui      = (const int*)d_in[0];
    const int*   vi      = (const int*)d_in[1];
    const int*   ei      = (const int*)d_in[2];
    const int*   et      = (const int*)d_in[3];
    const float* ew      = (const float*)d_in[4];
    const float* emb     = (const float*)d_in[5];
    const float* w1_rel  = (const float*)d_in[6];
    const float* w1_root = (const float*)d_in[7];
    const float* b1      = (const float*)d_in[8];
    const float* ln_g    = (const float*)d_in[9];
    const float* ln_b    = (const float*)d_in[10];
    const float* w2_rel  = (const float*)d_in[11];
    const float* w2_root = (const float*)d_in[12];
    const float* b2      = (const float*)d_in[13];
    const float* mw0     = (const float*)d_in[14];
    const float* mb0     = (const float*)d_in[15];
    const float* mw1     = (const float*)d_in[16];
    const float* mb1     = (const float*)d_in[17];
    const float* mw2     = (const float*)d_in[18];
    const float* mb2     = (const float*)d_in[19];
    const float* ow      = (const float*)d_in[20];
    const float* ob      = (const float*)d_in[21];
    float* out = (float*)d_out;

    const int N = N_NODES, E = N_EDGES, B = NBATCH;

    unsigned* Ap    = (unsigned*)d_ws;                 // [2][N][128] packed
    unsigned* xslot = Ap + (size_t)2 * N * EMBD;       // packed emb -> packed x1
    int2*     srec   = (int2*)(xslot + (size_t)N * EMBD);
    int*      cursor = (int*)(srec + E);
    int*      bsum   = cursor + N;

    // Wt planes after bsum, 64-byte aligned.
    char* wt0 = (char*)(bsum + NCHUNK);
    wt0 = (char*)(((uintptr_t)wt0 + 63) & ~(uintptr_t)63);
    unsigned short* WtH1 = (unsigned short*)wt0;
    unsigned short* WtL1 = WtH1 + 128 * 384;
    unsigned short* WtH2 = WtL1 + 128 * 384;
    unsigned short* WtL2 = WtH2 + 128 * 384;
    const size_t need_wt = (size_t)((char*)(WtL2 + 128 * 384) - (char*)d_ws);
    const bool have_wt = (ws_size >= need_wt);

    float* x2 = (float*)Ap;    // gemm-2 fp32 output, aliases Ap[0] rows

    // ---- Preprocess: pack emb + histogram; pre-split weights ----
    hipMemsetAsync(cursor, 0, N * sizeof(int), stream);
    pack_hist<<<(N * EMBD + 255) / 256, 256, 0, stream>>>(emb, xslot, ei, cursor, N * EMBD, E);
    if (have_wt)
        wpack_kernel<<<128, 384, 0, stream>>>(w1_rel, w1_root, w2_rel, w2_root,
                                              WtH1, WtL1, WtH2, WtL2);

    // ---- Sort edges by dst node (once; shared by both layers) ----
    scan_local<<<NCHUNK, 256, 0, stream>>>(cursor, bsum, N);
    scan_bsum<<<1, 128, 0, stream>>>(bsum);
    scan_add<<<NCHUNK, 256, 0, stream>>>(cursor, bsum, N);
    bucket_kernel<<<(E + 255) / 256, 256, 0, stream>>>(ei, et, ew, cursor, srec, E);

    const int ggrid = (N + 127) / 128;

    // ---- Layer 1: accum -> MFMA GEMM + bias + ReLU + LN (packed out) ----
    accum_csr<<<N / 4, 256, 0, stream>>>(xslot, srec, cursor, Ap, N);
    if (have_wt)
        gemm_mfma<true><<<ggrid, 256, 0, stream>>>(
            Ap, Ap + (size_t)N * EMBD, xslot, WtH1, WtL1,
            w1_rel, w1_root, b1, ln_g, ln_b, (void*)xslot, N, 1);
    else
        gemm_mfma<false><<<ggrid, 256, 0, stream>>>(
            Ap, Ap + (size_t)N * EMBD, xslot, nullptr, nullptr,
            w1_rel, w1_root, b1, ln_g, ln_b, (void*)xslot, N, 1);

    // ---- Layer 2: accum -> MFMA GEMM + bias (fp32 out) ----
    accum_csr<<<N / 4, 256, 0, stream>>>(xslot, srec, cursor, Ap, N);
    if (have_wt)
        gemm_mfma<true><<<ggrid, 256, 0, stream>>>(
            Ap, Ap + (size_t)N * EMBD, xslot, WtH2, WtL2,
            w2_rel, w2_root, b2, nullptr, nullptr, (void*)x2, N, 0);
    else
        gemm_mfma<false><<<ggrid, 256, 0, stream>>>(
            Ap, Ap + (size_t)N * EMBD, xslot, nullptr, nullptr,
            w2_rel, w2_root, b2, nullptr, nullptr, (void*)x2, N, 0);

    // ---- Head ----
    head_kernel<<<B / 16, 256, 0, stream>>>(
        x2, ui, vi, mw0, mb0, mw1, mb1, mw2, mb2, ow, ob, out, B);
}

// Round 9
// 553.678 us; speedup vs baseline: 1.0274x; 1.0274x over previous
//
#include <hip/hip_runtime.h>
#include <cstddef>
#include <cstdint>

// Problem constants (match reference setup_inputs()).
#define N_NODES 100000
#define N_EDGES 640000
#define EMBD    128
#define NBATCH  16384
#define CHUNK   1024
#define NCHUNK  ((N_NODES + CHUNK - 1) / CHUNK)   // 98

// MFMA fragment types (guide §3: bf16 16x16x32 -> short8 / float4).
typedef short bf16x8 __attribute__((ext_vector_type(8)));
typedef float f32x4  __attribute__((ext_vector_type(4)));

// ---------------------------------------------------------------------------
// Split-bf16: uint32 = bf16(x) [hi16] | bf16(x - hi) [lo16], RNE both.
// a*b via ah*bh + ah*bl + al*bh (3 MFMAs) drops only lo*lo (~2^-18 rel).
// ---------------------------------------------------------------------------
__device__ __forceinline__ unsigned pack_split(float x) {
    unsigned u  = __float_as_uint(x);
    unsigned hi = (u + 0x7fffu + ((u >> 16) & 1u)) & 0xffff0000u;
    float    lo = x - __uint_as_float(hi);
    unsigned ul = __float_as_uint(lo);
    unsigned lw = ((ul + 0x7fffu + ((ul >> 16) & 1u)) >> 16) & 0xffffu;
    return hi | lw;
}
__device__ __forceinline__ float unpack_split(unsigned u) {
    return __uint_as_float(u & 0xffff0000u) + __uint_as_float(u << 16);
}

// ---------------------------------------------------------------------------
// Fused: pack embedding to split-bf16 + per-dst-node edge histogram.
// ---------------------------------------------------------------------------
__global__ __launch_bounds__(256) void pack_hist(
    const float* __restrict__ emb, unsigned* __restrict__ xslot,
    const int* __restrict__ ei, int* __restrict__ cursor, int n, int E)
{
    const int i = blockIdx.x * 256 + threadIdx.x;
    if (i < n) xslot[i] = pack_split(emb[i]);
    if (i < E) atomicAdd(&cursor[ei[E + i]], 1);
}

// ---------------------------------------------------------------------------
// Pre-split both layers' weights into TRANSPOSED bf16 hi/lo planes:
// Wt*[col][k], k=0..383 (rows 0-255 = w_rel flat, 256-383 = w_root).
// ---------------------------------------------------------------------------
__global__ void wpack_kernel(
    const float* __restrict__ w1_rel, const float* __restrict__ w1_root,
    const float* __restrict__ w2_rel, const float* __restrict__ w2_root,
    unsigned short* __restrict__ WtH1, unsigned short* __restrict__ WtL1,
    unsigned short* __restrict__ WtH2, unsigned short* __restrict__ WtL2)
{
    const int col = blockIdx.x;
    const int k   = threadIdx.x;
    const size_t o = (size_t)col * 384 + k;
    {
        const float x = (k < 256) ? w1_rel[(size_t)k * EMBD + col]
                                  : w1_root[(size_t)(k - 256) * EMBD + col];
        const unsigned p = pack_split(x);
        WtH1[o] = (unsigned short)(p >> 16);
        WtL1[o] = (unsigned short)(p & 0xffffu);
    }
    {
        const float x = (k < 256) ? w2_rel[(size_t)k * EMBD + col]
                                  : w2_root[(size_t)(k - 256) * EMBD + col];
        const unsigned p = pack_split(x);
        WtH2[o] = (unsigned short)(p >> 16);
        WtL2[o] = (unsigned short)(p & 0xffffu);
    }
}

// ---------------------------------------------------------------------------
// Hierarchical exclusive scan (counts -> starts), in place.
// ---------------------------------------------------------------------------
__global__ __launch_bounds__(256) void scan_local(
    int* __restrict__ cursor, int* __restrict__ bsum, int n)
{
    __shared__ int part[256];
    const int t    = threadIdx.x;
    const int base = blockIdx.x * CHUNK + t * 4;
    int v[4];
    int s = 0;
#pragma unroll
    for (int i = 0; i < 4; ++i) {
        const int idx = base + i;
        v[i] = (idx < n) ? cursor[idx] : 0;
        s += v[i];
    }
    part[t] = s;
    __syncthreads();
    for (int off = 1; off < 256; off <<= 1) {
        const int add = (t >= off) ? part[t - off] : 0;
        __syncthreads();
        part[t] += add;
        __syncthreads();
    }
    if (t == 255) bsum[blockIdx.x] = part[255];
    int run = (t == 0) ? 0 : part[t - 1];
#pragma unroll
    for (int i = 0; i < 4; ++i) {
        const int idx = base + i;
        if (idx < n) { cursor[idx] = run; run += v[i]; }
    }
}

__global__ __launch_bounds__(128) void scan_bsum(int* __restrict__ bsum)
{
    __shared__ int part[128];
    const int t = threadIdx.x;
    const int v = (t < NCHUNK) ? bsum[t] : 0;
    part[t] = v;
    __syncthreads();
    for (int off = 1; off < 128; off <<= 1) {
        const int add = (t >= off) ? part[t - off] : 0;
        __syncthreads();
        part[t] += add;
        __syncthreads();
    }
    if (t < NCHUNK) bsum[t] = part[t] - v;    // exclusive
}

__global__ __launch_bounds__(256) void scan_add(
    int* __restrict__ cursor, const int* __restrict__ bsum, int n)
{
    const int off  = bsum[blockIdx.x];
    const int base = blockIdx.x * CHUNK + threadIdx.x * 4;
#pragma unroll
    for (int i = 0; i < 4; ++i) {
        const int idx = base + i;
        if (idx < n) cursor[idx] += off;
    }
}

// ---------------------------------------------------------------------------
// Bucket edges into dst-sorted order. After this, cursor[n] == END of node
// n's run. Record: src (17b) | rel (1b @17) in .x, weight bits in .y.
// ---------------------------------------------------------------------------
__global__ __launch_bounds__(256) void bucket_kernel(
    const int* __restrict__ ei, const int* __restrict__ et,
    const float* __restrict__ ew, int* __restrict__ cursor,
    int2* __restrict__ srec, int E)
{
    const int e = blockIdx.x * 256 + threadIdx.x;
    if (e >= E) return;
    const int src = ei[e];
    const int dst = ei[E + e];
    const int r   = et[e];
    const int pos = atomicAdd(&cursor[dst], 1);
    srec[pos] = make_int2(src | (r << 17), __float_as_int(ew[e]));
}

// ---------------------------------------------------------------------------
// One wave per dst node: gathers PACKED split-bf16 rows (uint2/lane),
// fp32 register accumulation of both relations, packed stores. No atomics.
// ---------------------------------------------------------------------------
__global__ __launch_bounds__(256) void accum_csr(
    const unsigned* __restrict__ xp, const int2* __restrict__ srec,
    const int* __restrict__ cursor, unsigned* __restrict__ Ap, int N)
{
    const int wid  = blockIdx.x * 4 + (threadIdx.x >> 6);   // dst node
    const int lane = threadIdx.x & 63;
    const int s = (wid == 0) ? 0 : cursor[wid - 1];
    const int e = cursor[wid];

    float ax = 0.f, ay = 0.f, bx = 0.f, by = 0.f;
    int i = s;
    for (; i + 3 < e; i += 4) {
        const int2 r0 = srec[i];
        const int2 r1 = srec[i + 1];
        const int2 r2 = srec[i + 2];
        const int2 r3 = srec[i + 3];
        const uint2 g0 = ((const uint2*)(xp + (size_t)(r0.x & 0x1FFFF) * EMBD))[lane];
        const uint2 g1 = ((const uint2*)(xp + (size_t)(r1.x & 0x1FFFF) * EMBD))[lane];
        const uint2 g2 = ((const uint2*)(xp + (size_t)(r2.x & 0x1FFFF) * EMBD))[lane];
        const uint2 g3 = ((const uint2*)(xp + (size_t)(r3.x & 0x1FFFF) * EMBD))[lane];
        const float w0 = __int_as_float(r0.y);
        const float w1 = __int_as_float(r1.y);
        const float w2 = __int_as_float(r2.y);
        const float w3 = __int_as_float(r3.y);
        {
            const float vx = unpack_split(g0.x), vy = unpack_split(g0.y);
            if (r0.x & (1 << 17)) { bx += vx * w0; by += vy * w0; }
            else                  { ax += vx * w0; ay += vy * w0; }
        }
        {
            const float vx = unpack_split(g1.x), vy = unpack_split(g1.y);
            if (r1.x & (1 << 17)) { bx += vx * w1; by += vy * w1; }
            else                  { ax += vx * w1; ay += vy * w1; }
        }
        {
            const float vx = unpack_split(g2.x), vy = unpack_split(g2.y);
            if (r2.x & (1 << 17)) { bx += vx * w2; by += vy * w2; }
            else                  { ax += vx * w2; ay += vy * w2; }
        }
        {
            const float vx = unpack_split(g3.x), vy = unpack_split(g3.y);
            if (r3.x & (1 << 17)) { bx += vx * w3; by += vy * w3; }
            else                  { ax += vx * w3; ay += vy * w3; }
        }
    }
    for (; i < e; ++i) {
        const int2 r0 = srec[i];
        const uint2 g0 = ((const uint2*)(xp + (size_t)(r0.x & 0x1FFFF) * EMBD))[lane];
        const float w0 = __int_as_float(r0.y);
        const float vx = unpack_split(g0.x), vy = unpack_split(g0.y);
        if (r0.x & (1 << 17)) { bx += vx * w0; by += vy * w0; }
        else                  { ax += vx * w0; ay += vy * w0; }
    }
    ((uint2*)(Ap + (size_t)wid * EMBD))[lane]       = make_uint2(pack_split(ax), pack_split(ay));
    ((uint2*)(Ap + ((size_t)N + wid) * EMBD))[lane] = make_uint2(pack_split(bx), pack_split(by));
}

// ---------------------------------------------------------------------------
// Split-bf16 MFMA GEMM: out[M,128] = (S0|S1|S2)[M,384] @ W[384,128] + bias.
// A-ONLY register prefetch: au* (16 VGPRs) loaded for chunk kc+1 right after
// the post-stage barrier, in flight across chunk kc's 48 MFMAs. B is a pure
// uint4 copy from pre-split Wt planes (L2-hot, latency sits in stage phase).
// History: r6 (no Wt, no prefetch) 73us — B pack VALU accidentally covered
// A latency; r7 (A+B prefetch + min-waves bound) spilled, 101us; r8 (Wt,
// no prefetch) 109us — bare latency exposed. This variant = r8 + A prefetch.
// Fragment layouts (m89/m120 verified): A[m=lane&15][k=quad*8+j];
// C/D col=lane&15, row=quad*4+reg. LDS rows 80 B so b128 reads are cheap.
// Each block reads only rows [m0,m0+128) of S* and writes the same rows of
// out strictly after all its reads -> out may alias any S*.
// ---------------------------------------------------------------------------
template <bool HAVE_WT>
__global__ __launch_bounds__(256) void gemm_mfma(
    const unsigned* __restrict__ S0, const unsigned* __restrict__ S1,
    const unsigned* __restrict__ S2,
    const unsigned short* __restrict__ WtH, const unsigned short* __restrict__ WtL,
    const float* __restrict__ wrel, const float* __restrict__ wroot,
    const float* __restrict__ bias, const float* __restrict__ lng,
    const float* __restrict__ lnb, void* __restrict__ outv,
    int M, int do_ln)
{
    __shared__ unsigned short AsH[128 * 40], AsL[128 * 40];   // 10 KB each
    __shared__ unsigned short BsH[128 * 40], BsL[128 * 40];
    __shared__ float lnbuf[2][128][2];

    const int t    = threadIdx.x;
    const int wave = t >> 6;
    const int lane = t & 63;
    const int q    = lane >> 4;
    const int n    = lane & 15;
    const int wrow = wave & 1;
    const int wcol = wave >> 1;
    const int m0   = blockIdx.x * 128;

    const int arow   = t >> 1;       // 0..127
    const int ahalf  = t & 1;        // which 16-elem half of the 32-k chunk
    const int bcol   = t & 127;
    const int bplane = t >> 7;       // 0 = hi, 1 = lo

    f32x4 acc[4][4];
#pragma unroll
    for (int rt = 0; rt < 4; ++rt)
#pragma unroll
        for (int ct = 0; ct < 4; ++ct)
            acc[rt][ct] = (f32x4){0.f, 0.f, 0.f, 0.f};

    uint4 au0, au1, au2, au3;        // A prefetch registers (16 VGPRs)
    auto loadA = [&](int kc) {
        const unsigned* Sp = (kc < 4) ? S0 : (kc < 8) ? S1 : S2;
        const int rg = m0 + arow;
        if (rg < M) {
            const unsigned* p = Sp + (size_t)rg * EMBD + (kc & 3) * 32 + ahalf * 16;
            au0 = *(const uint4*)(p);
            au1 = *(const uint4*)(p + 4);
            au2 = *(const uint4*)(p + 8);
            au3 = *(const uint4*)(p + 12);
        } else {
            au0 = au1 = au2 = au3 = make_uint4(0u, 0u, 0u, 0u);
        }
    };

    loadA(0);

    for (int kc = 0; kc < 12; ++kc) {
        __syncthreads();   // previous chunk's frag reads done before overwrite

        // ---- A stage: de-interleave prefetched regs -> split planes ----
        {
            const unsigned uu[16] = {au0.x, au0.y, au0.z, au0.w,
                                     au1.x, au1.y, au1.z, au1.w,
                                     au2.x, au2.y, au2.z, au2.w,
                                     au3.x, au3.y, au3.z, au3.w};
            unsigned dh[8], dl[8];
#pragma unroll
            for (int i = 0; i < 8; ++i) {
                const unsigned e0 = uu[2 * i], e1 = uu[2 * i + 1];
                dh[i] = (e1 & 0xffff0000u) | (e0 >> 16);
                dl[i] = (e1 << 16) | (e0 & 0xffffu);
            }
            uint4* pH = (uint4*)(AsH + arow * 40 + ahalf * 16);
            uint4* pL = (uint4*)(AsL + arow * 40 + ahalf * 16);
            pH[0] = make_uint4(dh[0], dh[1], dh[2], dh[3]);
            pH[1] = make_uint4(dh[4], dh[5], dh[6], dh[7]);
            pL[0] = make_uint4(dl[0], dl[1], dl[2], dl[3]);
            pL[1] = make_uint4(dl[4], dl[5], dl[6], dl[7]);
        }
        // ---- B stage ----
        if (HAVE_WT) {
            // Pure copy: 64 B of one plane of one column's 32-k chunk.
            const unsigned short* W = bplane ? WtL : WtH;
            const uint4* p = (const uint4*)(W + (size_t)bcol * 384 + kc * 32);
            uint4* pB = (uint4*)((bplane ? BsL : BsH) + bcol * 40);
            pB[0] = p[0]; pB[1] = p[1]; pB[2] = p[2]; pB[3] = p[3];
        } else {
            // Fallback: split fp32 W on the fly (16 values, both planes).
            const int bkh = t >> 7;
            unsigned pk[16];
#pragma unroll
            for (int j = 0; j < 16; ++j) {
                const int kv = kc * 32 + bkh * 16 + j;
                const float x = (kv < 256) ? wrel[(size_t)kv * EMBD + bcol]
                                           : wroot[(size_t)(kv - 256) * EMBD + bcol];
                pk[j] = pack_split(x);
            }
            unsigned dh[8], dl[8];
#pragma unroll
            for (int i = 0; i < 8; ++i) {
                const unsigned e0 = pk[2 * i], e1 = pk[2 * i + 1];
                dh[i] = (e1 & 0xffff0000u) | (e0 >> 16);
                dl[i] = (e1 << 16) | (e0 & 0xffffu);
            }
            uint4* pH = (uint4*)(BsH + bcol * 40 + bkh * 16);
            uint4* pL = (uint4*)(BsL + bcol * 40 + bkh * 16);
            pH[0] = make_uint4(dh[0], dh[1], dh[2], dh[3]);
            pH[1] = make_uint4(dh[4], dh[5], dh[6], dh[7]);
            pL[0] = make_uint4(dl[0], dl[1], dl[2], dl[3]);
            pL[1] = make_uint4(dl[4], dl[5], dl[6], dl[7]);
        }
        __syncthreads();

        if (kc < 11) loadA(kc + 1);   // global loads in flight across MFMAs

        // ---- fragments + MFMA ----
        bf16x8 ah[4], al[4];
#pragma unroll
        for (int rt = 0; rt < 4; ++rt) {
            const int r = wrow * 64 + rt * 16 + n;
            ah[rt] = *(const bf16x8*)&AsH[r * 40 + q * 8];
            al[rt] = *(const bf16x8*)&AsL[r * 40 + q * 8];
        }
#pragma unroll
        for (int ct = 0; ct < 4; ++ct) {
            const int c = wcol * 64 + ct * 16 + n;
            const bf16x8 bh = *(const bf16x8*)&BsH[c * 40 + q * 8];
            const bf16x8 bl = *(const bf16x8*)&BsL[c * 40 + q * 8];
#pragma unroll
            for (int rt = 0; rt < 4; ++rt) {
                acc[rt][ct] = __builtin_amdgcn_mfma_f32_16x16x32_bf16(ah[rt], bh, acc[rt][ct], 0, 0, 0);
                acc[rt][ct] = __builtin_amdgcn_mfma_f32_16x16x32_bf16(ah[rt], bl, acc[rt][ct], 0, 0, 0);
                acc[rt][ct] = __builtin_amdgcn_mfma_f32_16x16x32_bf16(al[rt], bh, acc[rt][ct], 0, 0, 0);
            }
        }
    }

    // ---- epilogue ----
    float bb[4], gg[4], tb[4];
#pragma unroll
    for (int ct = 0; ct < 4; ++ct) {
        const int c = wcol * 64 + ct * 16 + n;
        bb[ct] = bias[c];
        gg[ct] = do_ln ? lng[c] : 0.f;
        tb[ct] = do_ln ? lnb[c] : 0.f;
    }

    if (do_ln) {
#pragma unroll
        for (int rt = 0; rt < 4; ++rt)
#pragma unroll
            for (int r = 0; r < 4; ++r) {
                float s = 0.f, sq = 0.f;
#pragma unroll
                for (int ct = 0; ct < 4; ++ct) {
                    float v = acc[rt][ct][r] + bb[ct];
                    v = fmaxf(v, 0.f);
                    acc[rt][ct][r] = v;
                    s += v; sq += v * v;
                }
#pragma unroll
                for (int off = 1; off < 16; off <<= 1) {
                    s  += __shfl_xor(s,  off, 64);
                    sq += __shfl_xor(sq, off, 64);
                }
                if (n == 0) {
                    const int row = wrow * 64 + rt * 16 + q * 4 + r;
                    lnbuf[wcol][row][0] = s;
                    lnbuf[wcol][row][1] = sq;
                }
            }
        __syncthreads();
        unsigned* outp = (unsigned*)outv;
#pragma unroll
        for (int rt = 0; rt < 4; ++rt)
#pragma unroll
            for (int r = 0; r < 4; ++r) {
                const int row = wrow * 64 + rt * 16 + q * 4 + r;
                const int rg  = m0 + row;
                const float s    = lnbuf[0][row][0] + lnbuf[1][row][0];
                const float sq   = lnbuf[0][row][1] + lnbuf[1][row][1];
                const float mu   = s * (1.0f / 128.0f);
                const float var  = sq * (1.0f / 128.0f) - mu * mu;
                const float rstd = rsqrtf(var + 1e-5f);
                if (rg < M) {
#pragma unroll
                    for (int ct = 0; ct < 4; ++ct) {
                        const int c = wcol * 64 + ct * 16 + n;
                        const float v = (acc[rt][ct][r] - mu) * rstd * gg[ct] + tb[ct];
                        outp[(size_t)rg * EMBD + c] = pack_split(v);
                    }
                }
            }
    } else {
        float* outp = (float*)outv;
#pragma unroll
        for (int rt = 0; rt < 4; ++rt)
#pragma unroll
            for (int r = 0; r < 4; ++r) {
                const int rg = m0 + wrow * 64 + rt * 16 + q * 4 + r;
                if (rg < M) {
#pragma unroll
                    for (int ct = 0; ct < 4; ++ct) {
                        const int c = wcol * 64 + ct * 16 + n;
                        outp[(size_t)rg * EMBD + c] = acc[rt][ct][r] + bb[ct];
                    }
                }
            }
    }
}

// ---------------------------------------------------------------------------
// Fused head: gather u/v, l2 norms, GMF, MLP 256->128->64->32, out proj,
// sigmoid. 16 batch rows per 256-thread block, everything staged in LDS.
// ---------------------------------------------------------------------------
__global__ __launch_bounds__(256) void head_kernel(
    const float* __restrict__ x2, const int* __restrict__ ui, const int* __restrict__ vi,
    const float* __restrict__ mw0, const float* __restrict__ mb0,
    const float* __restrict__ mw1, const float* __restrict__ mb1,
    const float* __restrict__ mw2, const float* __restrict__ mb2,
    const float* __restrict__ ow, const float* __restrict__ ob,
    float* __restrict__ out, int B)
{
    __shared__ float h0[16][256];
    __shared__ float h1[16][128];
    __shared__ float h2[16][64];
    __shared__ float h3[16][32];
    __shared__ float ps_u[16][16], ps_v[16][16];
    __shared__ float inv_nunv[16];
    __shared__ float pg[16][16], ph[16][16];

    const int t   = threadIdx.x;
    const int bb0 = blockIdx.x * 16;

    for (int r = 0; r < 16; ++r) {
        const int b   = bb0 + r;
        const int idx = (t < 128) ? ui[b] : vi[b];
        const int c   = t & 127;
        h0[r][t] = x2[(size_t)idx * EMBD + c];
    }
    __syncthreads();

    {
        const int row = t >> 4, sub = t & 15;
        float su = 0.f, sv = 0.f;
#pragma unroll
        for (int k = 0; k < 8; ++k) {
            const float a = h0[row][sub + 16 * k];       su += a * a;
            const float b = h0[row][128 + sub + 16 * k]; sv += b * b;
        }
        ps_u[row][sub] = su; ps_v[row][sub] = sv;
    }
    __syncthreads();
    if (t < 16) {
        float su = 0.f, sv = 0.f;
#pragma unroll
        for (int k = 0; k < 16; ++k) { su += ps_u[t][k]; sv += ps_v[t][k]; }
        const float nu = fmaxf(sqrtf(su), 1e-12f);
        const float nv = fmaxf(sqrtf(sv), 1e-12f);
        inv_nunv[t] = 1.0f / (nu * nv);
    }
    __syncthreads();

    {
        const int c = t & 127, rr = t >> 7;
        float acc[8];
#pragma unroll
        for (int j = 0; j < 8; ++j) acc[j] = 0.f;
        for (int i = 0; i < 256; i += 4) {
            const float w0 = mw0[(i + 0) * 128 + c];
            const float w1 = mw0[(i + 1) * 128 + c];
            const float w2 = mw0[(i + 2) * 128 + c];
            const float w3 = mw0[(i + 3) * 128 + c];
#pragma unroll
            for (int j = 0; j < 8; ++j) {
                const float4 a = *(const float4*)&h0[rr * 8 + j][i];
                acc[j] += a.x * w0 + a.y * w1 + a.z * w2 + a.w * w3;
            }
        }
        const float bv = mb0[c];
#pragma unroll
        for (int j = 0; j < 8; ++j) h1[rr * 8 + j][c] = fmaxf(acc[j] + bv, 0.f);
    }
    __syncthreads();

    {
        const int c = t & 63, g = t >> 6;
        float acc[4] = {0.f, 0.f, 0.f, 0.f};
        for (int i = 0; i < 128; i += 4) {
            const float w0 = mw1[(i + 0) * 64 + c];
            const float w1 = mw1[(i + 1) * 64 + c];
            const float w2 = mw1[(i + 2) * 64 + c];
            const float w3 = mw1[(i + 3) * 64 + c];
#pragma unroll
            for (int j = 0; j < 4; ++j) {
                const float4 a = *(const float4*)&h1[g * 4 + j][i];
                acc[j] += a.x * w0 + a.y * w1 + a.z * w2 + a.w * w3;
            }
        }
        const float bv = mb1[c];
#pragma unroll
        for (int j = 0; j < 4; ++j) h2[g * 4 + j][c] = fmaxf(acc[j] + bv, 0.f);
    }
    __syncthreads();

    {
        const int c = t & 31, g = t >> 5;
        float acc[2] = {0.f, 0.f};
        for (int i = 0; i < 64; i += 4) {
            const float w0 = mw2[(i + 0) * 32 + c];
            const float w1 = mw2[(i + 1) * 32 + c];
            const float w2 = mw2[(i + 2) * 32 + c];
            const float w3 = mw2[(i + 3) * 32 + c];
#pragma unroll
            for (int j = 0; j < 2; ++j) {
                const float4 a = *(const float4*)&h2[g * 2 + j][i];
                acc[j] += a.x * w0 + a.y * w1 + a.z * w2 + a.w * w3;
            }
        }
        const float bv = mb2[c];
#pragma unroll
        for (int j = 0; j < 2; ++j) h3[g * 2 + j][c] = fmaxf(acc[j] + bv, 0.f);
    }
    __syncthreads();

    {
        const int row = t >> 4, sub = t & 15;
        float pgv = 0.f;
#pragma unroll
        for (int k = 0; k < 8; ++k) {
            const int c = sub + 16 * k;
            pgv += h0[row][c] * h0[row][128 + c] * ow[c];
        }
        const float phv = h3[row][sub]      * ow[128 + sub]
                        + h3[row][sub + 16] * ow[144 + sub];
        pg[row][sub] = pgv; ph[row][sub] = phv;
    }
    __syncthreads();
    if (t < 16) {
        float sg = 0.f, sh = 0.f;
#pragma unroll
        for (int k = 0; k < 16; ++k) { sg += pg[t][k]; sh += ph[t][k]; }
        const float z = sg * inv_nunv[t] + sh + ob[0];
        out[bb0 + t] = 1.0f / (1.0f + expf(-z));
    }
}

// ---------------------------------------------------------------------------
// Launch. ws layout (~159.5 MB; Wt planes guarded by ws_size check):
//   Ap[2][N][128]  u32 102.4 MB  (packed aggregates; gemm-2 writes fp32 x2
//                                 into Ap[0] rows, row-aliased safe)
//   xslot[N][128]  u32  51.2 MB  (packed emb -> packed x1, row-aliased)
//   srec[E] int2         5.12 MB
//   cursor[N]            0.4 MB
//   bsum[NCHUNK]         ~400 B
//   WtH1/WtL1/WtH2/WtL2  4 x 96 KB (pre-split transposed weight planes)
// ---------------------------------------------------------------------------
extern "C" void kernel_launch(void* const* d_in, const int* in_sizes, int n_in,
                              void* d_out, int out_size, void* d_ws, size_t ws_size,
                              hipStream_t stream)
{
    const int*   ui      = (const int*)d_in[0];
    const int*   vi      = (const int*)d_in[1];
    const int*   ei      = (const int*)d_in[2];
    const int*   et      = (const int*)d_in[3];
    const float* ew      = (const float*)d_in[4];
    const float* emb     = (const float*)d_in[5];
    const float* w1_rel  = (const float*)d_in[6];
    const float* w1_root = (const float*)d_in[7];
    const float* b1      = (const float*)d_in[8];
    const float* ln_g    = (const float*)d_in[9];
    const float* ln_b    = (const float*)d_in[10];
    const float* w2_rel  = (const float*)d_in[11];
    const float* w2_root = (const float*)d_in[12];
    const float* b2      = (const float*)d_in[13];
    const float* mw0     = (const float*)d_in[14];
    const float* mb0     = (const float*)d_in[15];
    const float* mw1     = (const float*)d_in[16];
    const float* mb1     = (const float*)d_in[17];
    const float* mw2     = (const float*)d_in[18];
    const float* mb2     = (const float*)d_in[19];
    const float* ow      = (const float*)d_in[20];
    const float* ob      = (const float*)d_in[21];
    float* out = (float*)d_out;

    const int N = N_NODES, E = N_EDGES, B = NBATCH;

    unsigned* Ap    = (unsigned*)d_ws;                 // [2][N][128] packed
    unsigned* xslot = Ap + (size_t)2 * N * EMBD;       // packed emb -> packed x1
    int2*     srec   = (int2*)(xslot + (size_t)N * EMBD);
    int*      cursor = (int*)(srec + E);
    int*      bsum   = cursor + N;

    // Wt planes after bsum, 64-byte aligned.
    char* wt0 = (char*)(bsum + NCHUNK);
    wt0 = (char*)(((uintptr_t)wt0 + 63) & ~(uintptr_t)63);
    unsigned short* WtH1 = (unsigned short*)wt0;
    unsigned short* WtL1 = WtH1 + 128 * 384;
    unsigned short* WtH2 = WtL1 + 128 * 384;
    unsigned short* WtL2 = WtH2 + 128 * 384;
    const size_t need_wt = (size_t)((char*)(WtL2 + 128 * 384) - (char*)d_ws);
    const bool have_wt = (ws_size >= need_wt);

    float* x2 = (float*)Ap;    // gemm-2 fp32 output, aliases Ap[0] rows

    // ---- Preprocess: pack emb + histogram; pre-split weights ----
    hipMemsetAsync(cursor, 0, N * sizeof(int), stream);
    pack_hist<<<(N * EMBD + 255) / 256, 256, 0, stream>>>(emb, xslot, ei, cursor, N * EMBD, E);
    if (have_wt)
        wpack_kernel<<<128, 384, 0, stream>>>(w1_rel, w1_root, w2_rel, w2_root,
                                              WtH1, WtL1, WtH2, WtL2);

    // ---- Sort edges by dst node (once; shared by both layers) ----
    scan_local<<<NCHUNK, 256, 0, stream>>>(cursor, bsum, N);
    scan_bsum<<<1, 128, 0, stream>>>(bsum);
    scan_add<<<NCHUNK, 256, 0, stream>>>(cursor, bsum, N);
    bucket_kernel<<<(E + 255) / 256, 256, 0, stream>>>(ei, et, ew, cursor, srec, E);

    const int ggrid = (N + 127) / 128;

    // ---- Layer 1: accum -> MFMA GEMM + bias + ReLU + LN (packed out) ----
    accum_csr<<<N / 4, 256, 0, stream>>>(xslot, srec, cursor, Ap, N);
    if (have_wt)
        gemm_mfma<true><<<ggrid, 256, 0, stream>>>(
            Ap, Ap + (size_t)N * EMBD, xslot, WtH1, WtL1,
            w1_rel, w1_root, b1, ln_g, ln_b, (void*)xslot, N, 1);
    else
        gemm_mfma<false><<<ggrid, 256, 0, stream>>>(
            Ap, Ap + (size_t)N * EMBD, xslot, nullptr, nullptr,
            w1_rel, w1_root, b1, ln_g, ln_b, (void*)xslot, N, 1);

    // ---- Layer 2: accum -> MFMA GEMM + bias (fp32 out) ----
    accum_csr<<<N / 4, 256, 0, stream>>>(xslot, srec, cursor, Ap, N);
    if (have_wt)
        gemm_mfma<true><<<ggrid, 256, 0, stream>>>(
            Ap, Ap + (size_t)N * EMBD, xslot, WtH2, WtL2,
            w2_rel, w2_root, b2, nullptr, nullptr, (void*)x2, N, 0);
    else
        gemm_mfma<false><<<ggrid, 256, 0, stream>>>(
            Ap, Ap + (size_t)N * EMBD, xslot, nullptr, nullptr,
            w2_rel, w2_root, b2, nullptr, nullptr, (void*)x2, N, 0);

    // ---- Head ----
    head_kernel<<<B / 16, 256, 0, stream>>>(
        x2, ui, vi, mw0, mb0, mw1, mb1, mw2, mb2, ow, ob, out, B);
}

// Round 10
// 499.694 us; speedup vs baseline: 1.1384x; 1.1080x over previous
//
#include <hip/hip_runtime.h>
#include <cstddef>
#include <cstdint>

// Problem constants (match reference setup_inputs()).
#define N_NODES 100000
#define N_EDGES 640000
#define EMBD    128
#define NBATCH  16384
#define CHUNK   1024
#define NCHUNK  ((N_NODES + CHUNK - 1) / CHUNK)   // 98

// MFMA fragment types (guide §3: bf16 16x16x32 -> short8 / float4).
typedef short bf16x8 __attribute__((ext_vector_type(8)));
typedef float f32x4  __attribute__((ext_vector_type(4)));

// ---------------------------------------------------------------------------
// Split-bf16: uint32 = bf16(x) [hi16] | bf16(x - hi) [lo16], RNE both.
// a*b via ah*bh + ah*bl + al*bh (3 MFMAs) drops only lo*lo (~2^-18 rel).
// ---------------------------------------------------------------------------
__device__ __forceinline__ unsigned pack_split(float x) {
    unsigned u  = __float_as_uint(x);
    unsigned hi = (u + 0x7fffu + ((u >> 16) & 1u)) & 0xffff0000u;
    float    lo = x - __uint_as_float(hi);
    unsigned ul = __float_as_uint(lo);
    unsigned lw = ((ul + 0x7fffu + ((ul >> 16) & 1u)) >> 16) & 0xffffu;
    return hi | lw;
}
__device__ __forceinline__ float unpack_split(unsigned u) {
    return __uint_as_float(u & 0xffff0000u) + __uint_as_float(u << 16);
}

// ---------------------------------------------------------------------------
// Fused: pack embedding to split-bf16 + per-dst-node edge histogram.
// ---------------------------------------------------------------------------
__global__ __launch_bounds__(256) void pack_hist(
    const float* __restrict__ emb, unsigned* __restrict__ xslot,
    const int* __restrict__ ei, int* __restrict__ cursor, int n, int E)
{
    const int i = blockIdx.x * 256 + threadIdx.x;
    if (i < n) xslot[i] = pack_split(emb[i]);
    if (i < E) atomicAdd(&cursor[ei[E + i]], 1);
}

// ---------------------------------------------------------------------------
// Hierarchical exclusive scan (counts -> starts), in place.
// ---------------------------------------------------------------------------
__global__ __launch_bounds__(256) void scan_local(
    int* __restrict__ cursor, int* __restrict__ bsum, int n)
{
    __shared__ int part[256];
    const int t    = threadIdx.x;
    const int base = blockIdx.x * CHUNK + t * 4;
    int v[4];
    int s = 0;
#pragma unroll
    for (int i = 0; i < 4; ++i) {
        const int idx = base + i;
        v[i] = (idx < n) ? cursor[idx] : 0;
        s += v[i];
    }
    part[t] = s;
    __syncthreads();
    for (int off = 1; off < 256; off <<= 1) {
        const int add = (t >= off) ? part[t - off] : 0;
        __syncthreads();
        part[t] += add;
        __syncthreads();
    }
    if (t == 255) bsum[blockIdx.x] = part[255];
    int run = (t == 0) ? 0 : part[t - 1];
#pragma unroll
    for (int i = 0; i < 4; ++i) {
        const int idx = base + i;
        if (idx < n) { cursor[idx] = run; run += v[i]; }
    }
}

__global__ __launch_bounds__(128) void scan_bsum(int* __restrict__ bsum)
{
    __shared__ int part[128];
    const int t = threadIdx.x;
    const int v = (t < NCHUNK) ? bsum[t] : 0;
    part[t] = v;
    __syncthreads();
    for (int off = 1; off < 128; off <<= 1) {
        const int add = (t >= off) ? part[t - off] : 0;
        __syncthreads();
        part[t] += add;
        __syncthreads();
    }
    if (t < NCHUNK) bsum[t] = part[t] - v;    // exclusive
}

__global__ __launch_bounds__(256) void scan_add(
    int* __restrict__ cursor, const int* __restrict__ bsum, int n)
{
    const int off  = bsum[blockIdx.x];
    const int base = blockIdx.x * CHUNK + threadIdx.x * 4;
#pragma unroll
    for (int i = 0; i < 4; ++i) {
        const int idx = base + i;
        if (idx < n) cursor[idx] += off;
    }
}

// ---------------------------------------------------------------------------
// Bucket edges into dst-sorted order. After this, cursor[n] == END of node
// n's run. Record: src (17b) | rel (1b @17) in .x, weight bits in .y.
// ---------------------------------------------------------------------------
__global__ __launch_bounds__(256) void bucket_kernel(
    const int* __restrict__ ei, const int* __restrict__ et,
    const float* __restrict__ ew, int* __restrict__ cursor,
    int2* __restrict__ srec, int E)
{
    const int e = blockIdx.x * 256 + threadIdx.x;
    if (e >= E) return;
    const int src = ei[e];
    const int dst = ei[E + e];
    const int r   = et[e];
    const int pos = atomicAdd(&cursor[dst], 1);
    srec[pos] = make_int2(src | (r << 17), __float_as_int(ew[e]));
}

// ---------------------------------------------------------------------------
// One wave per dst node: gathers PACKED split-bf16 rows (uint2/lane),
// fp32 register accumulation of both relations, packed stores. No atomics.
// ---------------------------------------------------------------------------
__global__ __launch_bounds__(256) void accum_csr(
    const unsigned* __restrict__ xp, const int2* __restrict__ srec,
    const int* __restrict__ cursor, unsigned* __restrict__ Ap, int N)
{
    const int wid  = blockIdx.x * 4 + (threadIdx.x >> 6);   // dst node
    const int lane = threadIdx.x & 63;
    const int s = (wid == 0) ? 0 : cursor[wid - 1];
    const int e = cursor[wid];

    float ax = 0.f, ay = 0.f, bx = 0.f, by = 0.f;
    int i = s;
    for (; i + 3 < e; i += 4) {
        const int2 r0 = srec[i];
        const int2 r1 = srec[i + 1];
        const int2 r2 = srec[i + 2];
        const int2 r3 = srec[i + 3];
        const uint2 g0 = ((const uint2*)(xp + (size_t)(r0.x & 0x1FFFF) * EMBD))[lane];
        const uint2 g1 = ((const uint2*)(xp + (size_t)(r1.x & 0x1FFFF) * EMBD))[lane];
        const uint2 g2 = ((const uint2*)(xp + (size_t)(r2.x & 0x1FFFF) * EMBD))[lane];
        const uint2 g3 = ((const uint2*)(xp + (size_t)(r3.x & 0x1FFFF) * EMBD))[lane];
        const float w0 = __int_as_float(r0.y);
        const float w1 = __int_as_float(r1.y);
        const float w2 = __int_as_float(r2.y);
        const float w3 = __int_as_float(r3.y);
        {
            const float vx = unpack_split(g0.x), vy = unpack_split(g0.y);
            if (r0.x & (1 << 17)) { bx += vx * w0; by += vy * w0; }
            else                  { ax += vx * w0; ay += vy * w0; }
        }
        {
            const float vx = unpack_split(g1.x), vy = unpack_split(g1.y);
            if (r1.x & (1 << 17)) { bx += vx * w1; by += vy * w1; }
            else                  { ax += vx * w1; ay += vy * w1; }
        }
        {
            const float vx = unpack_split(g2.x), vy = unpack_split(g2.y);
            if (r2.x & (1 << 17)) { bx += vx * w2; by += vy * w2; }
            else                  { ax += vx * w2; ay += vy * w2; }
        }
        {
            const float vx = unpack_split(g3.x), vy = unpack_split(g3.y);
            if (r3.x & (1 << 17)) { bx += vx * w3; by += vy * w3; }
            else                  { ax += vx * w3; ay += vy * w3; }
        }
    }
    for (; i < e; ++i) {
        const int2 r0 = srec[i];
        const uint2 g0 = ((const uint2*)(xp + (size_t)(r0.x & 0x1FFFF) * EMBD))[lane];
        const float w0 = __int_as_float(r0.y);
        const float vx = unpack_split(g0.x), vy = unpack_split(g0.y);
        if (r0.x & (1 << 17)) { bx += vx * w0; by += vy * w0; }
        else                  { ax += vx * w0; ay += vy * w0; }
    }
    ((uint2*)(Ap + (size_t)wid * EMBD))[lane]       = make_uint2(pack_split(ax), pack_split(ay));
    ((uint2*)(Ap + ((size_t)N + wid) * EMBD))[lane] = make_uint2(pack_split(bx), pack_split(by));
}

// ---------------------------------------------------------------------------
// Split-bf16 MFMA GEMM: out[M,128] = (S0|S1|S2)[M,384] @ W[384,128] + bias.
// History lesson (r6=73us, r7=101 spill, r8=109, r9=100):
//   - B staging MUST be coalesced-global: thread t loads W[k*128 + (t&127)]
//     (consecutive lanes -> consecutive addresses). The r7/r8 "pre-split
//     transposed Wt[col][k]" copy had a 768B lane stride -> sector-amplified
//     scatter -> +36us. Reverted to r6's on-the-fly pack_split staging; its
//     VALU work overlaps other blocks' MFMA phases (m114 co-schedule).
//   - A-only register prefetch (16 VGPRs) is worth ~9us (r8->r9) and does
//     not spill at ~144 VGPR (3 waves/SIMD = the LDS-imposed residency).
//     Issued between A-stage and B-stage so the load sits under the B pack
//     VALU and the MFMA phase.
// Fragment layouts (m89/m120 verified): A[m=lane&15][k=quad*8+j];
// C/D col=lane&15, row=quad*4+reg. LDS rows 80 B so b128 reads are cheap.
// Each block reads only rows [m0,m0+128) of S* and writes the same rows of
// out strictly after all its reads -> out may alias any S*.
// ---------------------------------------------------------------------------
__global__ __launch_bounds__(256) void gemm_mfma(
    const unsigned* __restrict__ S0, const unsigned* __restrict__ S1,
    const unsigned* __restrict__ S2,
    const float* __restrict__ wrel, const float* __restrict__ wroot,
    const float* __restrict__ bias, const float* __restrict__ lng,
    const float* __restrict__ lnb, void* __restrict__ outv,
    int M, int do_ln)
{
    __shared__ unsigned short AsH[128 * 40], AsL[128 * 40];   // 10 KB each
    __shared__ unsigned short BsH[128 * 40], BsL[128 * 40];
    __shared__ float lnbuf[2][128][2];

    const int t    = threadIdx.x;
    const int wave = t >> 6;
    const int lane = t & 63;
    const int q    = lane >> 4;
    const int n    = lane & 15;
    const int wrow = wave & 1;
    const int wcol = wave >> 1;
    const int m0   = blockIdx.x * 128;

    const int arow  = t >> 1;        // 0..127
    const int ahalf = t & 1;         // which 16-elem half of the 32-k chunk
    const int bcol  = t & 127;
    const int bkh   = t >> 7;        // which 16-k half

    f32x4 acc[4][4];
#pragma unroll
    for (int rt = 0; rt < 4; ++rt)
#pragma unroll
        for (int ct = 0; ct < 4; ++ct)
            acc[rt][ct] = (f32x4){0.f, 0.f, 0.f, 0.f};

    uint4 au0, au1, au2, au3;        // A prefetch registers (16 VGPRs)
    auto loadA = [&](int kc) {
        const unsigned* Sp = (kc < 4) ? S0 : (kc < 8) ? S1 : S2;
        const int rg = m0 + arow;
        if (rg < M) {
            const unsigned* p = Sp + (size_t)rg * EMBD + (kc & 3) * 32 + ahalf * 16;
            au0 = *(const uint4*)(p);
            au1 = *(const uint4*)(p + 4);
            au2 = *(const uint4*)(p + 8);
            au3 = *(const uint4*)(p + 12);
        } else {
            au0 = au1 = au2 = au3 = make_uint4(0u, 0u, 0u, 0u);
        }
    };

    loadA(0);

    for (int kc = 0; kc < 12; ++kc) {
        __syncthreads();   // previous chunk's frag reads done before overwrite

        // ---- A stage: de-interleave prefetched regs -> split planes ----
        {
            const unsigned uu[16] = {au0.x, au0.y, au0.z, au0.w,
                                     au1.x, au1.y, au1.z, au1.w,
                                     au2.x, au2.y, au2.z, au2.w,
                                     au3.x, au3.y, au3.z, au3.w};
            unsigned dh[8], dl[8];
#pragma unroll
            for (int i = 0; i < 8; ++i) {
                const unsigned e0 = uu[2 * i], e1 = uu[2 * i + 1];
                dh[i] = (e1 & 0xffff0000u) | (e0 >> 16);
                dl[i] = (e1 << 16) | (e0 & 0xffffu);
            }
            uint4* pH = (uint4*)(AsH + arow * 40 + ahalf * 16);
            uint4* pL = (uint4*)(AsL + arow * 40 + ahalf * 16);
            pH[0] = make_uint4(dh[0], dh[1], dh[2], dh[3]);
            pH[1] = make_uint4(dh[4], dh[5], dh[6], dh[7]);
            pL[0] = make_uint4(dl[0], dl[1], dl[2], dl[3]);
            pL[1] = make_uint4(dl[4], dl[5], dl[6], dl[7]);
        }

        if (kc < 11) loadA(kc + 1);   // loads in flight under B pack + MFMAs

        // ---- B stage: coalesced fp32 loads + on-the-fly split (r6 form) ----
        {
            const float* Wsrc = (kc < 8) ? (wrel + (size_t)kc * 32 * EMBD)
                                         : (wroot + (size_t)(kc - 8) * 32 * EMBD);
            unsigned pk[16];
#pragma unroll
            for (int j = 0; j < 16; ++j)
                pk[j] = pack_split(Wsrc[(size_t)(bkh * 16 + j) * EMBD + bcol]);
            unsigned dh[8], dl[8];
#pragma unroll
            for (int i = 0; i < 8; ++i) {
                const unsigned e0 = pk[2 * i], e1 = pk[2 * i + 1];
                dh[i] = (e1 & 0xffff0000u) | (e0 >> 16);
                dl[i] = (e1 << 16) | (e0 & 0xffffu);
            }
            uint4* pH = (uint4*)(BsH + bcol * 40 + bkh * 16);
            uint4* pL = (uint4*)(BsL + bcol * 40 + bkh * 16);
            pH[0] = make_uint4(dh[0], dh[1], dh[2], dh[3]);
            pH[1] = make_uint4(dh[4], dh[5], dh[6], dh[7]);
            pL[0] = make_uint4(dl[0], dl[1], dl[2], dl[3]);
            pL[1] = make_uint4(dl[4], dl[5], dl[6], dl[7]);
        }
        __syncthreads();

        // ---- fragments + MFMA ----
        bf16x8 ah[4], al[4];
#pragma unroll
        for (int rt = 0; rt < 4; ++rt) {
            const int r = wrow * 64 + rt * 16 + n;
            ah[rt] = *(const bf16x8*)&AsH[r * 40 + q * 8];
            al[rt] = *(const bf16x8*)&AsL[r * 40 + q * 8];
        }
#pragma unroll
        for (int ct = 0; ct < 4; ++ct) {
            const int c = wcol * 64 + ct * 16 + n;
            const bf16x8 bh = *(const bf16x8*)&BsH[c * 40 + q * 8];
            const bf16x8 bl = *(const bf16x8*)&BsL[c * 40 + q * 8];
#pragma unroll
            for (int rt = 0; rt < 4; ++rt) {
                acc[rt][ct] = __builtin_amdgcn_mfma_f32_16x16x32_bf16(ah[rt], bh, acc[rt][ct], 0, 0, 0);
                acc[rt][ct] = __builtin_amdgcn_mfma_f32_16x16x32_bf16(ah[rt], bl, acc[rt][ct], 0, 0, 0);
                acc[rt][ct] = __builtin_amdgcn_mfma_f32_16x16x32_bf16(al[rt], bh, acc[rt][ct], 0, 0, 0);
            }
        }
    }

    // ---- epilogue ----
    float bb[4], gg[4], tb[4];
#pragma unroll
    for (int ct = 0; ct < 4; ++ct) {
        const int c = wcol * 64 + ct * 16 + n;
        bb[ct] = bias[c];
        gg[ct] = do_ln ? lng[c] : 0.f;
        tb[ct] = do_ln ? lnb[c] : 0.f;
    }

    if (do_ln) {
#pragma unroll
        for (int rt = 0; rt < 4; ++rt)
#pragma unroll
            for (int r = 0; r < 4; ++r) {
                float s = 0.f, sq = 0.f;
#pragma unroll
                for (int ct = 0; ct < 4; ++ct) {
                    float v = acc[rt][ct][r] + bb[ct];
                    v = fmaxf(v, 0.f);
                    acc[rt][ct][r] = v;
                    s += v; sq += v * v;
                }
#pragma unroll
                for (int off = 1; off < 16; off <<= 1) {
                    s  += __shfl_xor(s,  off, 64);
                    sq += __shfl_xor(sq, off, 64);
                }
                if (n == 0) {
                    const int row = wrow * 64 + rt * 16 + q * 4 + r;
                    lnbuf[wcol][row][0] = s;
                    lnbuf[wcol][row][1] = sq;
                }
            }
        __syncthreads();
        unsigned* outp = (unsigned*)outv;
#pragma unroll
        for (int rt = 0; rt < 4; ++rt)
#pragma unroll
            for (int r = 0; r < 4; ++r) {
                const int row = wrow * 64 + rt * 16 + q * 4 + r;
                const int rg  = m0 + row;
                const float s    = lnbuf[0][row][0] + lnbuf[1][row][0];
                const float sq   = lnbuf[0][row][1] + lnbuf[1][row][1];
                const float mu   = s * (1.0f / 128.0f);
                const float var  = sq * (1.0f / 128.0f) - mu * mu;
                const float rstd = rsqrtf(var + 1e-5f);
                if (rg < M) {
#pragma unroll
                    for (int ct = 0; ct < 4; ++ct) {
                        const int c = wcol * 64 + ct * 16 + n;
                        const float v = (acc[rt][ct][r] - mu) * rstd * gg[ct] + tb[ct];
                        outp[(size_t)rg * EMBD + c] = pack_split(v);
                    }
                }
            }
    } else {
        float* outp = (float*)outv;
#pragma unroll
        for (int rt = 0; rt < 4; ++rt)
#pragma unroll
            for (int r = 0; r < 4; ++r) {
                const int rg = m0 + wrow * 64 + rt * 16 + q * 4 + r;
                if (rg < M) {
#pragma unroll
                    for (int ct = 0; ct < 4; ++ct) {
                        const int c = wcol * 64 + ct * 16 + n;
                        outp[(size_t)rg * EMBD + c] = acc[rt][ct][r] + bb[ct];
                    }
                }
            }
    }
}

// ---------------------------------------------------------------------------
// Fused head: gather u/v, l2 norms, GMF, MLP 256->128->64->32, out proj,
// sigmoid. 16 batch rows per 256-thread block, everything staged in LDS.
// ---------------------------------------------------------------------------
__global__ __launch_bounds__(256) void head_kernel(
    const float* __restrict__ x2, const int* __restrict__ ui, const int* __restrict__ vi,
    const float* __restrict__ mw0, const float* __restrict__ mb0,
    const float* __restrict__ mw1, const float* __restrict__ mb1,
    const float* __restrict__ mw2, const float* __restrict__ mb2,
    const float* __restrict__ ow, const float* __restrict__ ob,
    float* __restrict__ out, int B)
{
    __shared__ float h0[16][256];
    __shared__ float h1[16][128];
    __shared__ float h2[16][64];
    __shared__ float h3[16][32];
    __shared__ float ps_u[16][16], ps_v[16][16];
    __shared__ float inv_nunv[16];
    __shared__ float pg[16][16], ph[16][16];

    const int t   = threadIdx.x;
    const int bb0 = blockIdx.x * 16;

    for (int r = 0; r < 16; ++r) {
        const int b   = bb0 + r;
        const int idx = (t < 128) ? ui[b] : vi[b];
        const int c   = t & 127;
        h0[r][t] = x2[(size_t)idx * EMBD + c];
    }
    __syncthreads();

    {
        const int row = t >> 4, sub = t & 15;
        float su = 0.f, sv = 0.f;
#pragma unroll
        for (int k = 0; k < 8; ++k) {
            const float a = h0[row][sub + 16 * k];       su += a * a;
            const float b = h0[row][128 + sub + 16 * k]; sv += b * b;
        }
        ps_u[row][sub] = su; ps_v[row][sub] = sv;
    }
    __syncthreads();
    if (t < 16) {
        float su = 0.f, sv = 0.f;
#pragma unroll
        for (int k = 0; k < 16; ++k) { su += ps_u[t][k]; sv += ps_v[t][k]; }
        const float nu = fmaxf(sqrtf(su), 1e-12f);
        const float nv = fmaxf(sqrtf(sv), 1e-12f);
        inv_nunv[t] = 1.0f / (nu * nv);
    }
    __syncthreads();

    {
        const int c = t & 127, rr = t >> 7;
        float acc[8];
#pragma unroll
        for (int j = 0; j < 8; ++j) acc[j] = 0.f;
        for (int i = 0; i < 256; i += 4) {
            const float w0 = mw0[(i + 0) * 128 + c];
            const float w1 = mw0[(i + 1) * 128 + c];
            const float w2 = mw0[(i + 2) * 128 + c];
            const float w3 = mw0[(i + 3) * 128 + c];
#pragma unroll
            for (int j = 0; j < 8; ++j) {
                const float4 a = *(const float4*)&h0[rr * 8 + j][i];
                acc[j] += a.x * w0 + a.y * w1 + a.z * w2 + a.w * w3;
            }
        }
        const float bv = mb0[c];
#pragma unroll
        for (int j = 0; j < 8; ++j) h1[rr * 8 + j][c] = fmaxf(acc[j] + bv, 0.f);
    }
    __syncthreads();

    {
        const int c = t & 63, g = t >> 6;
        float acc[4] = {0.f, 0.f, 0.f, 0.f};
        for (int i = 0; i < 128; i += 4) {
            const float w0 = mw1[(i + 0) * 64 + c];
            const float w1 = mw1[(i + 1) * 64 + c];
            const float w2 = mw1[(i + 2) * 64 + c];
            const float w3 = mw1[(i + 3) * 64 + c];
#pragma unroll
            for (int j = 0; j < 4; ++j) {
                const float4 a = *(const float4*)&h1[g * 4 + j][i];
                acc[j] += a.x * w0 + a.y * w1 + a.z * w2 + a.w * w3;
            }
        }
        const float bv = mb1[c];
#pragma unroll
        for (int j = 0; j < 4; ++j) h2[g * 4 + j][c] = fmaxf(acc[j] + bv, 0.f);
    }
    __syncthreads();

    {
        const int c = t & 31, g = t >> 5;
        float acc[2] = {0.f, 0.f};
        for (int i = 0; i < 64; i += 4) {
            const float w0 = mw2[(i + 0) * 32 + c];
            const float w1 = mw2[(i + 1) * 32 + c];
            const float w2 = mw2[(i + 2) * 32 + c];
            const float w3 = mw2[(i + 3) * 32 + c];
#pragma unroll
            for (int j = 0; j < 2; ++j) {
                const float4 a = *(const float4*)&h2[g * 2 + j][i];
                acc[j] += a.x * w0 + a.y * w1 + a.z * w2 + a.w * w3;
            }
        }
        const float bv = mb2[c];
#pragma unroll
        for (int j = 0; j < 2; ++j) h3[g * 2 + j][c] = fmaxf(acc[j] + bv, 0.f);
    }
    __syncthreads();

    {
        const int row = t >> 4, sub = t & 15;
        float pgv = 0.f;
#pragma unroll
        for (int k = 0; k < 8; ++k) {
            const int c = sub + 16 * k;
            pgv += h0[row][c] * h0[row][128 + c] * ow[c];
        }
        const float phv = h3[row][sub]      * ow[128 + sub]
                        + h3[row][sub + 16] * ow[144 + sub];
        pg[row][sub] = pgv; ph[row][sub] = phv;
    }
    __syncthreads();
    if (t < 16) {
        float sg = 0.f, sh = 0.f;
#pragma unroll
        for (int k = 0; k < 16; ++k) { sg += pg[t][k]; sh += ph[t][k]; }
        const float z = sg * inv_nunv[t] + sh + ob[0];
        out[bb0 + t] = 1.0f / (1.0f + expf(-z));
    }
}

// ---------------------------------------------------------------------------
// Launch. ws layout (~159.1 MB):
//   Ap[2][N][128]  u32 102.4 MB  (packed aggregates; gemm-2 writes fp32 x2
//                                 into Ap[0] rows, row-aliased safe)
//   xslot[N][128]  u32  51.2 MB  (packed emb -> packed x1, row-aliased)
//   srec[E] int2         5.12 MB
//   cursor[N]            0.4 MB
//   bsum[NCHUNK]         ~400 B
// ---------------------------------------------------------------------------
extern "C" void kernel_launch(void* const* d_in, const int* in_sizes, int n_in,
                              void* d_out, int out_size, void* d_ws, size_t ws_size,
                              hipStream_t stream)
{
    const int*   ui      = (const int*)d_in[0];
    const int*   vi      = (const int*)d_in[1];
    const int*   ei      = (const int*)d_in[2];
    const int*   et      = (const int*)d_in[3];
    const float* ew      = (const float*)d_in[4];
    const float* emb     = (const float*)d_in[5];
    const float* w1_rel  = (const float*)d_in[6];
    const float* w1_root = (const float*)d_in[7];
    const float* b1      = (const float*)d_in[8];
    const float* ln_g    = (const float*)d_in[9];
    const float* ln_b    = (const float*)d_in[10];
    const float* w2_rel  = (const float*)d_in[11];
    const float* w2_root = (const float*)d_in[12];
    const float* b2      = (const float*)d_in[13];
    const float* mw0     = (const float*)d_in[14];
    const float* mb0     = (const float*)d_in[15];
    const float* mw1     = (const float*)d_in[16];
    const float* mb1     = (const float*)d_in[17];
    const float* mw2     = (const float*)d_in[18];
    const float* mb2     = (const float*)d_in[19];
    const float* ow      = (const float*)d_in[20];
    const float* ob      = (const float*)d_in[21];
    float* out = (float*)d_out;

    const int N = N_NODES, E = N_EDGES, B = NBATCH;

    unsigned* Ap    = (unsigned*)d_ws;                 // [2][N][128] packed
    unsigned* xslot = Ap + (size_t)2 * N * EMBD;       // packed emb -> packed x1
    int2*     srec   = (int2*)(xslot + (size_t)N * EMBD);
    int*      cursor = (int*)(srec + E);
    int*      bsum   = cursor + N;

    float* x2 = (float*)Ap;    // gemm-2 fp32 output, aliases Ap[0] rows

    // ---- Preprocess: pack emb + histogram ----
    hipMemsetAsync(cursor, 0, N * sizeof(int), stream);
    pack_hist<<<(N * EMBD + 255) / 256, 256, 0, stream>>>(emb, xslot, ei, cursor, N * EMBD, E);

    // ---- Sort edges by dst node (once; shared by both layers) ----
    scan_local<<<NCHUNK, 256, 0, stream>>>(cursor, bsum, N);
    scan_bsum<<<1, 128, 0, stream>>>(bsum);
    scan_add<<<NCHUNK, 256, 0, stream>>>(cursor, bsum, N);
    bucket_kernel<<<(E + 255) / 256, 256, 0, stream>>>(ei, et, ew, cursor, srec, E);

    const int ggrid = (N + 127) / 128;

    // ---- Layer 1: accum -> MFMA GEMM + bias + ReLU + LN (packed out) ----
    accum_csr<<<N / 4, 256, 0, stream>>>(xslot, srec, cursor, Ap, N);
    gemm_mfma<<<ggrid, 256, 0, stream>>>(
        Ap, Ap + (size_t)N * EMBD, xslot,
        w1_rel, w1_root, b1, ln_g, ln_b, (void*)xslot, N, 1);

    // ---- Layer 2: accum -> MFMA GEMM + bias (fp32 out) ----
    accum_csr<<<N / 4, 256, 0, stream>>>(xslot, srec, cursor, Ap, N);
    gemm_mfma<<<ggrid, 256, 0, stream>>>(
        Ap, Ap + (size_t)N * EMBD, xslot,
        w2_rel, w2_root, b2, nullptr, nullptr, (void*)x2, N, 0);

    // ---- Head ----
    head_kernel<<<B / 16, 256, 0, stream>>>(
        x2, ui, vi, mw0, mb0, mw1, mb1, mw2, mb2, ow, ob, out, B);
}